// Round 12
// baseline (264.223 us; speedup 1.0000x reference)
//
#include <hip/hip_runtime.h>
#include <hip/hip_bf16.h>

#define NF     32
#define ED     128
#define NBATCH 2048
#define NPAIRS 496
#define BM     128
#define SLICE_ROWS (NBATCH / 8)   // 256 rows per XCD slice
#define NITER  (SLICE_ROWS / BM)  // 2 M-blocks per slice

typedef __attribute__((ext_vector_type(8))) short short8;   // 8 bf16 (MFMA A/B frag)
typedef __attribute__((ext_vector_type(4))) short short4v;  // 4 bf16
typedef __attribute__((ext_vector_type(4))) float f32x4;

#define FEMB_BF_ELEMS ((size_t)NF * NBATCH * ED)            // 8,388,608
#define W_BF_ELEMS    ((size_t)NPAIRS * ED * ED)            // 8,126,464
#define WS_NEEDED     ((FEMB_BF_ELEMS + W_BF_ELEMS) * 2)    // ~33 MB

// LDS-only barrier (r10 lever, kept): orders LDS without draining the VMEM
// queue (NT stores + prefetch loads keep flowing across iterations).
#define LGKM_BARRIER() asm volatile("s_waitcnt lgkmcnt(0)\n\ts_barrier" ::: "memory")

__device__ __forceinline__ short f2bf(float x) {
    union { __hip_bfloat16 b; short s; } v;
    v.b = __float2bfloat16(x);
    return v.s;
}
__device__ __forceinline__ float bf2f(short s) {
    union { unsigned int u; float f; } v;
    v.u = ((unsigned int)(unsigned short)s) << 16;
    return v.f;
}

// ---------- Pre-pass 1: femb fp32 [b][f][d] -> bf16 field-major [f][b][d] ----------
__global__ __launch_bounds__(256)
void prep_femb(const float* __restrict__ femb, unsigned short* __restrict__ fb) {
    int n = blockIdx.x * 256 + threadIdx.x;       // 1,048,576 threads x 8 elems
    int d8 = n & 15;
    int b  = (n >> 4) & (NBATCH - 1);
    int f  = n >> 15;
    const float* s = femb + ((size_t)b * NF + f) * ED + d8 * 8;
    f32x4 lo = __builtin_nontemporal_load(reinterpret_cast<const f32x4*>(s));
    f32x4 hi = __builtin_nontemporal_load(reinterpret_cast<const f32x4*>(s + 4));
    short8 pk;
    pk[0]=f2bf(lo.x); pk[1]=f2bf(lo.y); pk[2]=f2bf(lo.z); pk[3]=f2bf(lo.w);
    pk[4]=f2bf(hi.x); pk[5]=f2bf(hi.y); pk[6]=f2bf(hi.z); pk[7]=f2bf(hi.w);
    *reinterpret_cast<short8*>(fb + ((size_t)f * NBATCH + b) * ED + d8 * 8) = pk;
}

// ---------- Pre-pass 2: W fp32 -> bf16 flat [p][e][d] ----------
__global__ __launch_bounds__(256)
void prep_w(const float* __restrict__ W, unsigned short* __restrict__ wb) {
    size_t n = (size_t)blockIdx.x * 256 + threadIdx.x;
    size_t idx8 = n * 8;
    if (idx8 >= W_BF_ELEMS) return;
    const float* s = W + idx8;
    f32x4 lo = __builtin_nontemporal_load(reinterpret_cast<const f32x4*>(s));
    f32x4 hi = __builtin_nontemporal_load(reinterpret_cast<const f32x4*>(s + 4));
    short8 pk;
    pk[0]=f2bf(lo.x); pk[1]=f2bf(lo.y); pk[2]=f2bf(lo.z); pk[3]=f2bf(lo.w);
    pk[4]=f2bf(hi.x); pk[5]=f2bf(hi.y); pk[6]=f2bf(hi.z); pk[7]=f2bf(hi.w);
    *reinterpret_cast<short8*>(wb + idx8) = pk;
}

// LDS layout (both tiles): 128 rows x 256 B, swizzled:
//   byte(row, col) = row*256 + (col ^ ((row & 15) << 4))   -> conflict-free ds_read_b128

// ---------- Main kernel: r10 structure + XCD-pinned batch slices ----------
// bid = p*8 + slice; slice = bid&7 -> XCD (round-robin dispatch). Each XCD
// runs ALL 496 pairs over ITS fixed 256-row batch slice: femb working set
// per XCD = 32 fields x 256 rows x 256 B = 2 MB -> L2-RESIDENT all kernel.
// vi/vj reads become L2 hits; fabric carries only writes + W (L3-shared).
__global__ __launch_bounds__(512, 2)
void bilinear_bf16(const unsigned short* __restrict__ fb,
                   const unsigned short* __restrict__ wb,
                   float* __restrict__ out)
{
    __shared__ unsigned char ldsW[128 * 256];
    __shared__ unsigned char ldsA[128 * 256];

    const int bid   = blockIdx.x;
    const int p     = bid >> 3;          // pair 0..495
    const int slice = bid & 7;           // XCD-pinned batch slice
    const int bbase = slice * SLICE_ROWS;

    int fi = 0, rem = p;
    while (rem >= NF - 1 - fi) { rem -= NF - 1 - fi; ++fi; }
    const int fj = fi + 1 + rem;

    const int t    = threadIdx.x;
    const int lane = t & 63;
    const int wave = t >> 6;

    // ---- Stage W once: bf16, NT (must NOT evict the hot femb L2 slice) ----
    {
        const unsigned short* wp = wb + (size_t)p * (ED * ED);
        #pragma unroll
        for (int it = 0; it < 4; ++it) {
            int idx8 = it * 4096 + t * 8;
            int e = idx8 >> 7, d = idx8 & 127;
            short8 pk = __builtin_nontemporal_load(
                reinterpret_cast<const short8*>(wp + idx8));
            *reinterpret_cast<short8*>(ldsW + e * 256 + ((d * 2) ^ ((e & 15) << 4))) = pk;
        }
    }

    // vi staging coords: thread covers rows {r_, r_+32, r_+64, r_+96} at d_..d_+7
    const int r_ = t >> 4;
    const int d_ = (t * 8) & 127;
    const unsigned short* fiPlane = fb + (size_t)fi * NBATCH * ED;
    const unsigned short* fjPlane = fb + (size_t)fj * NBATCH * ED;

    const int we  = wave & 3;       // e-quadrant
    const int wb_ = wave >> 2;      // b-half
    const int lhi = lane >> 4;
    const int llo = lane & 15;

    short8 stg[4];
    #pragma unroll
    for (int q = 0; q < 4; ++q)
        stg[q] = *reinterpret_cast<const short8*>(
            fiPlane + (size_t)(bbase + r_ + q * 32) * ED + d_);

    for (int mb = 0; mb < NITER; ++mb) {
        const int b0 = bbase + mb * BM;

        // ---- A-write: staged bf16 -> swizzled LDS ----
        #pragma unroll
        for (int q = 0; q < 4; ++q) {
            int r = r_ + q * 32;
            *reinterpret_cast<short8*>(ldsA + r * 256 + ((d_ * 2) ^ ((r & 15) << 4))) = stg[q];
        }
        LGKM_BARRIER();   // A visible; VMEM (stores/prefetch) NOT drained

        // ---- Issue next vi prefetch ----
        if (mb + 1 < NITER) {
            const unsigned short* base =
                fiPlane + (size_t)(bbase + (mb + 1) * BM + r_) * ED + d_;
            #pragma unroll
            for (int q = 0; q < 4; ++q)
                stg[q] = *reinterpret_cast<const short8*>(base + (size_t)q * 32 * ED);
        }

        // ---- Prefetch vj (bf16, L2-hit) for epilogue ----
        short4v vjr[4][2];
        #pragma unroll
        for (int ni = 0; ni < 4; ++ni) {
            int b = b0 + wb_ * 64 + ni * 16 + llo;
            const unsigned short* vj = fjPlane + (size_t)b * ED;
            #pragma unroll
            for (int mi = 0; mi < 2; ++mi) {
                int e0 = we * 32 + mi * 16 + lhi * 4;
                vjr[ni][mi] = *reinterpret_cast<const short4v*>(vj + e0);
            }
        }

        // ---- Compute: D[e][b] = W . vi^T ----
        f32x4 acc[2][4] = {};
        #pragma unroll
        for (int kk = 0; kk < 4; ++kk) {
            const int db = kk * 64 + lhi * 16;
            short8 a[2], b[4];
            #pragma unroll
            for (int mi = 0; mi < 2; ++mi) {
                int e = we * 32 + mi * 16 + llo;
                a[mi] = *reinterpret_cast<const short8*>(ldsW + e * 256 + (db ^ (llo << 4)));
            }
            #pragma unroll
            for (int ni = 0; ni < 4; ++ni) {
                int r = wb_ * 64 + ni * 16 + llo;
                b[ni] = *reinterpret_cast<const short8*>(ldsA + r * 256 + (db ^ (llo << 4)));
            }
            #pragma unroll
            for (int mi = 0; mi < 2; ++mi)
                #pragma unroll
                for (int ni = 0; ni < 4; ++ni)
                    acc[mi][ni] = __builtin_amdgcn_mfma_f32_16x16x32_bf16(a[mi], b[ni], acc[mi][ni], 0, 0, 0);
        }
        LGKM_BARRIER();   // ds_reads of ldsA done -> next iter may overwrite

        // ---- Epilogue: out = D * vj, NT stores ----
        #pragma unroll
        for (int ni = 0; ni < 4; ++ni) {
            int b = b0 + wb_ * 64 + ni * 16 + llo;
            float* op = out + ((size_t)b * NPAIRS + p) * ED;
            #pragma unroll
            for (int mi = 0; mi < 2; ++mi) {
                int e0 = we * 32 + mi * 16 + lhi * 4;
                short4v vs = vjr[ni][mi];
                f32x4 r = acc[mi][ni];
                f32x4 o;
                o.x = r[0] * bf2f(vs[0]); o.y = r[1] * bf2f(vs[1]);
                o.z = r[2] * bf2f(vs[2]); o.w = r[3] * bf2f(vs[3]);
                __builtin_nontemporal_store(o, reinterpret_cast<f32x4*>(op + e0));
            }
        }
    }
}

// ---------- Fallback (fp32 inputs) if ws too small ----------
__global__ __launch_bounds__(512, 2)
void bilinear_f32(const float* __restrict__ femb,
                  const float* __restrict__ W,
                  float* __restrict__ out)
{
    __shared__ unsigned char ldsW[128 * 256];
    __shared__ unsigned char ldsA[128 * 256];

    const int p = blockIdx.x;
    int fi = 0, rem = p;
    while (rem >= NF - 1 - fi) { rem -= NF - 1 - fi; ++fi; }
    const int fj = fi + 1 + rem;

    const int t    = threadIdx.x;
    const int lane = t & 63;
    const int wave = t >> 6;

    {
        const float* wp = W + (size_t)p * (ED * ED);
        #pragma unroll
        for (int it = 0; it < 4; ++it) {
            int idx8 = it * 4096 + t * 8;
            int e = idx8 >> 7, d = idx8 & 127;
            const float* s = wp + (size_t)e * ED + d;
            f32x4 lo = __builtin_nontemporal_load(reinterpret_cast<const f32x4*>(s));
            f32x4 hi = __builtin_nontemporal_load(reinterpret_cast<const f32x4*>(s + 4));
            short8 pk;
            pk[0]=f2bf(lo.x); pk[1]=f2bf(lo.y); pk[2]=f2bf(lo.z); pk[3]=f2bf(lo.w);
            pk[4]=f2bf(hi.x); pk[5]=f2bf(hi.y); pk[6]=f2bf(hi.z); pk[7]=f2bf(hi.w);
            *reinterpret_cast<short8*>(ldsW + e * 256 + ((d * 2) ^ ((e & 15) << 4))) = pk;
        }
    }

    const int r_ = t >> 4;
    const int d_ = (t * 8) & 127;
    const size_t ROWSTRIDE32 = (size_t)32 * NF * ED;

    const int we  = wave & 3;
    const int wb_ = wave >> 2;
    const int lhi = lane >> 4;
    const int llo = lane & 15;

    f32x4 stg[8];
    {
        const float* base = femb + ((size_t)r_ * NF + fi) * ED + d_;
        #pragma unroll
        for (int q = 0; q < 4; ++q) {
            const float* s = base + (size_t)q * ROWSTRIDE32;
            stg[2*q]   = *reinterpret_cast<const f32x4*>(s);
            stg[2*q+1] = *reinterpret_cast<const f32x4*>(s + 4);
        }
    }

    for (int mb = 0; mb < NBATCH / BM; ++mb) {
        const int b0 = mb * BM;
        #pragma unroll
        for (int q = 0; q < 4; ++q) {
            int r = r_ + q * 32;
            f32x4 lo = stg[2*q], hi = stg[2*q+1];
            short8 pk;
            pk[0]=f2bf(lo.x); pk[1]=f2bf(lo.y); pk[2]=f2bf(lo.z); pk[3]=f2bf(lo.w);
            pk[4]=f2bf(hi.x); pk[5]=f2bf(hi.y); pk[6]=f2bf(hi.z); pk[7]=f2bf(hi.w);
            *reinterpret_cast<short8*>(ldsA + r * 256 + ((d_ * 2) ^ ((r & 15) << 4))) = pk;
        }
        __syncthreads();

        if (mb + 1 < NBATCH / BM) {
            const float* base = femb + ((size_t)((mb + 1) * BM + r_) * NF + fi) * ED + d_;
            #pragma unroll
            for (int q = 0; q < 4; ++q) {
                const float* s = base + (size_t)q * ROWSTRIDE32;
                stg[2*q]   = *reinterpret_cast<const f32x4*>(s);
                stg[2*q+1] = *reinterpret_cast<const f32x4*>(s + 4);
            }
        }

        f32x4 vjr[4][2];
        #pragma unroll
        for (int ni = 0; ni < 4; ++ni) {
            int b = b0 + wb_ * 64 + ni * 16 + llo;
            const float* vj = femb + ((size_t)b * NF + fj) * ED;
            #pragma unroll
            for (int mi = 0; mi < 2; ++mi) {
                int e0 = we * 32 + mi * 16 + lhi * 4;
                vjr[ni][mi] = *reinterpret_cast<const f32x4*>(vj + e0);
            }
        }

        f32x4 acc[2][4] = {};
        #pragma unroll
        for (int kk = 0; kk < 4; ++kk) {
            const int db = kk * 64 + lhi * 16;
            short8 a[2], b[4];
            #pragma unroll
            for (int mi = 0; mi < 2; ++mi) {
                int e = we * 32 + mi * 16 + llo;
                a[mi] = *reinterpret_cast<const short8*>(ldsW + e * 256 + (db ^ (llo << 4)));
            }
            #pragma unroll
            for (int ni = 0; ni < 4; ++ni) {
                int r = wb_ * 64 + ni * 16 + llo;
                b[ni] = *reinterpret_cast<const short8*>(ldsA + r * 256 + (db ^ (llo << 4)));
            }
            #pragma unroll
            for (int mi = 0; mi < 2; ++mi)
                #pragma unroll
                for (int ni = 0; ni < 4; ++ni)
                    acc[mi][ni] = __builtin_amdgcn_mfma_f32_16x16x32_bf16(a[mi], b[ni], acc[mi][ni], 0, 0, 0);
        }
        __syncthreads();

        #pragma unroll
        for (int ni = 0; ni < 4; ++ni) {
            int b = b0 + wb_ * 64 + ni * 16 + llo;
            float* op = out + ((size_t)b * NPAIRS + p) * ED;
            #pragma unroll
            for (int mi = 0; mi < 2; ++mi) {
                int e0 = we * 32 + mi * 16 + lhi * 4;
                f32x4 v = vjr[ni][mi];
                f32x4 r = acc[mi][ni];
                f32x4 o;
                o.x = r[0] * v.x; o.y = r[1] * v.y;
                o.z = r[2] * v.z; o.w = r[3] * v.w;
                __builtin_nontemporal_store(o, reinterpret_cast<f32x4*>(op + e0));
            }
        }
    }
}

extern "C" void kernel_launch(void* const* d_in, const int* in_sizes, int n_in,
                              void* d_out, int out_size, void* d_ws, size_t ws_size,
                              hipStream_t stream) {
    (void)in_sizes; (void)n_in; (void)out_size;
    const float* femb = (const float*)d_in[0];
    const float* W    = (const float*)d_in[1];
    float* out        = (float*)d_out;

    if (ws_size >= WS_NEEDED) {
        unsigned short* fbp = (unsigned short*)d_ws;
        unsigned short* wbp = fbp + FEMB_BF_ELEMS;
        hipLaunchKernelGGL(prep_femb, dim3(FEMB_BF_ELEMS / 8 / 256), dim3(256), 0, stream, femb, fbp);
        hipLaunchKernelGGL(prep_w,    dim3((W_BF_ELEMS / 8 + 255) / 256), dim3(256), 0, stream, W, wbp);
        hipLaunchKernelGGL(bilinear_bf16, dim3(NPAIRS * 8), dim3(512), 0, stream, fbp, wbp, out);
    } else {
        hipLaunchKernelGGL(bilinear_f32, dim3(NPAIRS), dim3(512), 0, stream, femb, W, out);
    }
}

// Round 13
// 175.715 us; speedup vs baseline: 1.5037x; 1.5037x over previous
//
#include <hip/hip_runtime.h>
#include <hip/hip_bf16.h>

#define NF     32
#define ED     128
#define NBATCH 2048
#define NPAIRS 496
#define BM     128
#define NITER  (NBATCH / BM)   // 16 M-blocks per pair

typedef __attribute__((ext_vector_type(8))) short short8;   // 8 bf16 (MFMA A/B frag)
typedef __attribute__((ext_vector_type(4))) short short4v;  // 4 bf16
typedef __attribute__((ext_vector_type(4))) float f32x4;

#define FEMB_BF_ELEMS ((size_t)NF * NBATCH * ED)            // 8,388,608
#define W_BF_ELEMS    ((size_t)NPAIRS * ED * ED)            // 8,126,464
#define WS_NEEDED     ((FEMB_BF_ELEMS + W_BF_ELEMS) * 2)    // ~33 MB

#define PREP_FEMB_BLOCKS 4096   // FEMB_BF_ELEMS / 8 / 256
#define PREP_W_BLOCKS    3968   // W_BF_ELEMS / 8 / 256 (exact)

// LDS-only barrier (r10 lever): orders LDS without draining the VMEM queue
// (NT stores + prefetch loads keep flowing across iterations).
#define LGKM_BARRIER() asm volatile("s_waitcnt lgkmcnt(0)\n\ts_barrier" ::: "memory")

__device__ __forceinline__ short f2bf(float x) {
    union { __hip_bfloat16 b; short s; } v;
    v.b = __float2bfloat16(x);
    return v.s;
}
__device__ __forceinline__ float bf2f(short s) {
    union { unsigned int u; float f; } v;
    v.u = ((unsigned int)(unsigned short)s) << 16;
    return v.f;
}

// ---------- Merged pre-pass: femb -> bf16 field-major [f][b][d]; W -> bf16 flat ----------
__global__ __launch_bounds__(256)
void prep_all(const float* __restrict__ femb, const float* __restrict__ W,
              unsigned short* __restrict__ fb, unsigned short* __restrict__ wb) {
    int bid = blockIdx.x;
    if (bid < PREP_FEMB_BLOCKS) {
        int n = bid * 256 + threadIdx.x;          // x8 elems
        int d8 = n & 15;
        int b  = (n >> 4) & (NBATCH - 1);
        int f  = n >> 15;
        const float* s = femb + ((size_t)b * NF + f) * ED + d8 * 8;
        f32x4 lo = __builtin_nontemporal_load(reinterpret_cast<const f32x4*>(s));
        f32x4 hi = __builtin_nontemporal_load(reinterpret_cast<const f32x4*>(s + 4));
        short8 pk;
        pk[0]=f2bf(lo.x); pk[1]=f2bf(lo.y); pk[2]=f2bf(lo.z); pk[3]=f2bf(lo.w);
        pk[4]=f2bf(hi.x); pk[5]=f2bf(hi.y); pk[6]=f2bf(hi.z); pk[7]=f2bf(hi.w);
        *reinterpret_cast<short8*>(fb + ((size_t)f * NBATCH + b) * ED + d8 * 8) = pk;
    } else {
        size_t n = (size_t)(bid - PREP_FEMB_BLOCKS) * 256 + threadIdx.x;
        size_t idx8 = n * 8;
        const float* s = W + idx8;
        f32x4 lo = __builtin_nontemporal_load(reinterpret_cast<const f32x4*>(s));
        f32x4 hi = __builtin_nontemporal_load(reinterpret_cast<const f32x4*>(s + 4));
        short8 pk;
        pk[0]=f2bf(lo.x); pk[1]=f2bf(lo.y); pk[2]=f2bf(lo.z); pk[3]=f2bf(lo.w);
        pk[4]=f2bf(hi.x); pk[5]=f2bf(hi.y); pk[6]=f2bf(hi.z); pk[7]=f2bf(hi.w);
        *reinterpret_cast<short8*>(wb + idx8) = pk;
    }
}

// LDS layout (both tiles): 128 rows x 256 B, swizzled:
//   byte(row, col) = row*256 + (col ^ ((row & 15) << 4))   -> conflict-free ds_read_b128

// ---------- Main kernel: r10 structure + chunked pair->XCD swizzle ----------
// p = (bid&7)*62 + (bid>>3): XCD x (round-robin dispatch) runs pairs
// [62x, 62x+62), ALL co-resident (496 blocks fit device-wide). Consecutive
// pairs share fi (lexicographic bands) -> each XCD's vi working set is
// 2-4 fi planes (1-2 MB) -> L2-RESIDENT; vi fabric reads ~248 MB -> ~30 MB.
__global__ __launch_bounds__(512, 2)
void bilinear_bf16(const unsigned short* __restrict__ fb,
                   const unsigned short* __restrict__ wb,
                   float* __restrict__ out)
{
    __shared__ unsigned char ldsW[128 * 256];
    __shared__ unsigned char ldsA[128 * 256];

    const int bid = blockIdx.x;
    const int p   = (bid & 7) * (NPAIRS / 8) + (bid >> 3);   // chunked XCD swizzle

    int fi = 0, rem = p;
    while (rem >= NF - 1 - fi) { rem -= NF - 1 - fi; ++fi; }
    const int fj = fi + 1 + rem;

    const int t    = threadIdx.x;
    const int lane = t & 63;
    const int wave = t >> 6;

    // ---- Stage W once: bf16, NT (must not evict the hot fi planes in L2) ----
    {
        const unsigned short* wp = wb + (size_t)p * (ED * ED);
        #pragma unroll
        for (int it = 0; it < 4; ++it) {
            int idx8 = it * 4096 + t * 8;
            int e = idx8 >> 7, d = idx8 & 127;
            short8 pk = __builtin_nontemporal_load(
                reinterpret_cast<const short8*>(wp + idx8));
            *reinterpret_cast<short8*>(ldsW + e * 256 + ((d * 2) ^ ((e & 15) << 4))) = pk;
        }
    }

    // vi staging coords: thread covers rows {r_, r_+32, r_+64, r_+96} at d_..d_+7
    const int r_ = t >> 4;
    const int d_ = (t * 8) & 127;
    const unsigned short* fiPlane = fb + (size_t)fi * NBATCH * ED;
    const unsigned short* fjPlane = fb + (size_t)fj * NBATCH * ED;

    const int we  = wave & 3;       // e-quadrant
    const int wb_ = wave >> 2;      // b-half
    const int lhi = lane >> 4;
    const int llo = lane & 15;

    short8 stg[4];
    #pragma unroll
    for (int q = 0; q < 4; ++q)
        stg[q] = *reinterpret_cast<const short8*>(fiPlane + (size_t)(r_ + q * 32) * ED + d_);

    for (int mb = 0; mb < NITER; ++mb) {
        const int b0 = mb * BM;

        // ---- A-write: staged bf16 -> swizzled LDS ----
        #pragma unroll
        for (int q = 0; q < 4; ++q) {
            int r = r_ + q * 32;
            *reinterpret_cast<short8*>(ldsA + r * 256 + ((d_ * 2) ^ ((r & 15) << 4))) = stg[q];
        }
        LGKM_BARRIER();   // A visible; VMEM (stores/prefetch) NOT drained

        // ---- Issue next vi prefetch (L2-hit under the swizzle) ----
        if (mb + 1 < NITER) {
            const unsigned short* base = fiPlane + (size_t)((mb + 1) * BM + r_) * ED + d_;
            #pragma unroll
            for (int q = 0; q < 4; ++q)
                stg[q] = *reinterpret_cast<const short8*>(base + (size_t)q * 32 * ED);
        }

        // ---- Prefetch vj (bf16) for epilogue ----
        short4v vjr[4][2];
        #pragma unroll
        for (int ni = 0; ni < 4; ++ni) {
            int b = b0 + wb_ * 64 + ni * 16 + llo;
            const unsigned short* vj = fjPlane + (size_t)b * ED;
            #pragma unroll
            for (int mi = 0; mi < 2; ++mi) {
                int e0 = we * 32 + mi * 16 + lhi * 4;
                vjr[ni][mi] = *reinterpret_cast<const short4v*>(vj + e0);
            }
        }

        // ---- Compute: D[e][b] = W . vi^T ----
        f32x4 acc[2][4] = {};
        #pragma unroll
        for (int kk = 0; kk < 4; ++kk) {
            const int db = kk * 64 + lhi * 16;
            short8 a[2], b[4];
            #pragma unroll
            for (int mi = 0; mi < 2; ++mi) {
                int e = we * 32 + mi * 16 + llo;
                a[mi] = *reinterpret_cast<const short8*>(ldsW + e * 256 + (db ^ (llo << 4)));
            }
            #pragma unroll
            for (int ni = 0; ni < 4; ++ni) {
                int r = wb_ * 64 + ni * 16 + llo;
                b[ni] = *reinterpret_cast<const short8*>(ldsA + r * 256 + (db ^ (llo << 4)));
            }
            #pragma unroll
            for (int mi = 0; mi < 2; ++mi)
                #pragma unroll
                for (int ni = 0; ni < 4; ++ni)
                    acc[mi][ni] = __builtin_amdgcn_mfma_f32_16x16x32_bf16(a[mi], b[ni], acc[mi][ni], 0, 0, 0);
        }
        LGKM_BARRIER();   // ds_reads of ldsA done -> next iter may overwrite

        // ---- Epilogue: out = D * vj, NT stores ----
        #pragma unroll
        for (int ni = 0; ni < 4; ++ni) {
            int b = b0 + wb_ * 64 + ni * 16 + llo;
            float* op = out + ((size_t)b * NPAIRS + p) * ED;
            #pragma unroll
            for (int mi = 0; mi < 2; ++mi) {
                int e0 = we * 32 + mi * 16 + lhi * 4;
                short4v vs = vjr[ni][mi];
                f32x4 r = acc[mi][ni];
                f32x4 o;
                o.x = r[0] * bf2f(vs[0]); o.y = r[1] * bf2f(vs[1]);
                o.z = r[2] * bf2f(vs[2]); o.w = r[3] * bf2f(vs[3]);
                __builtin_nontemporal_store(o, reinterpret_cast<f32x4*>(op + e0));
            }
        }
    }
}

// ---------- Fallback (fp32 inputs) if ws too small ----------
__global__ __launch_bounds__(512, 2)
void bilinear_f32(const float* __restrict__ femb,
                  const float* __restrict__ W,
                  float* __restrict__ out)
{
    __shared__ unsigned char ldsW[128 * 256];
    __shared__ unsigned char ldsA[128 * 256];

    const int p = blockIdx.x;
    int fi = 0, rem = p;
    while (rem >= NF - 1 - fi) { rem -= NF - 1 - fi; ++fi; }
    const int fj = fi + 1 + rem;

    const int t    = threadIdx.x;
    const int lane = t & 63;
    const int wave = t >> 6;

    {
        const float* wp = W + (size_t)p * (ED * ED);
        #pragma unroll
        for (int it = 0; it < 4; ++it) {
            int idx8 = it * 4096 + t * 8;
            int e = idx8 >> 7, d = idx8 & 127;
            const float* s = wp + (size_t)e * ED + d;
            f32x4 lo = __builtin_nontemporal_load(reinterpret_cast<const f32x4*>(s));
            f32x4 hi = __builtin_nontemporal_load(reinterpret_cast<const f32x4*>(s + 4));
            short8 pk;
            pk[0]=f2bf(lo.x); pk[1]=f2bf(lo.y); pk[2]=f2bf(lo.z); pk[3]=f2bf(lo.w);
            pk[4]=f2bf(hi.x); pk[5]=f2bf(hi.y); pk[6]=f2bf(hi.z); pk[7]=f2bf(hi.w);
            *reinterpret_cast<short8*>(ldsW + e * 256 + ((d * 2) ^ ((e & 15) << 4))) = pk;
        }
    }

    const int r_ = t >> 4;
    const int d_ = (t * 8) & 127;
    const size_t ROWSTRIDE32 = (size_t)32 * NF * ED;

    const int we  = wave & 3;
    const int wb_ = wave >> 2;
    const int lhi = lane >> 4;
    const int llo = lane & 15;

    f32x4 stg[8];
    {
        const float* base = femb + ((size_t)r_ * NF + fi) * ED + d_;
        #pragma unroll
        for (int q = 0; q < 4; ++q) {
            const float* s = base + (size_t)q * ROWSTRIDE32;
            stg[2*q]   = *reinterpret_cast<const f32x4*>(s);
            stg[2*q+1] = *reinterpret_cast<const f32x4*>(s + 4);
        }
    }

    for (int mb = 0; mb < NITER; ++mb) {
        const int b0 = mb * BM;
        #pragma unroll
        for (int q = 0; q < 4; ++q) {
            int r = r_ + q * 32;
            f32x4 lo = stg[2*q], hi = stg[2*q+1];
            short8 pk;
            pk[0]=f2bf(lo.x); pk[1]=f2bf(lo.y); pk[2]=f2bf(lo.z); pk[3]=f2bf(lo.w);
            pk[4]=f2bf(hi.x); pk[5]=f2bf(hi.y); pk[6]=f2bf(hi.z); pk[7]=f2bf(hi.w);
            *reinterpret_cast<short8*>(ldsA + r * 256 + ((d_ * 2) ^ ((r & 15) << 4))) = pk;
        }
        __syncthreads();

        if (mb + 1 < NITER) {
            const float* base = femb + ((size_t)((mb + 1) * BM + r_) * NF + fi) * ED + d_;
            #pragma unroll
            for (int q = 0; q < 4; ++q) {
                const float* s = base + (size_t)q * ROWSTRIDE32;
                stg[2*q]   = *reinterpret_cast<const f32x4*>(s);
                stg[2*q+1] = *reinterpret_cast<const f32x4*>(s + 4);
            }
        }

        f32x4 vjr[4][2];
        #pragma unroll
        for (int ni = 0; ni < 4; ++ni) {
            int b = b0 + wb_ * 64 + ni * 16 + llo;
            const float* vj = femb + ((size_t)b * NF + fj) * ED;
            #pragma unroll
            for (int mi = 0; mi < 2; ++mi) {
                int e0 = we * 32 + mi * 16 + lhi * 4;
                vjr[ni][mi] = *reinterpret_cast<const f32x4*>(vj + e0);
            }
        }

        f32x4 acc[2][4] = {};
        #pragma unroll
        for (int kk = 0; kk < 4; ++kk) {
            const int db = kk * 64 + lhi * 16;
            short8 a[2], b[4];
            #pragma unroll
            for (int mi = 0; mi < 2; ++mi) {
                int e = we * 32 + mi * 16 + llo;
                a[mi] = *reinterpret_cast<const short8*>(ldsW + e * 256 + (db ^ (llo << 4)));
            }
            #pragma unroll
            for (int ni = 0; ni < 4; ++ni) {
                int r = wb_ * 64 + ni * 16 + llo;
                b[ni] = *reinterpret_cast<const short8*>(ldsA + r * 256 + (db ^ (llo << 4)));
            }
            #pragma unroll
            for (int mi = 0; mi < 2; ++mi)
                #pragma unroll
                for (int ni = 0; ni < 4; ++ni)
                    acc[mi][ni] = __builtin_amdgcn_mfma_f32_16x16x32_bf16(a[mi], b[ni], acc[mi][ni], 0, 0, 0);
        }
        __syncthreads();

        #pragma unroll
        for (int ni = 0; ni < 4; ++ni) {
            int b = b0 + wb_ * 64 + ni * 16 + llo;
            float* op = out + ((size_t)b * NPAIRS + p) * ED;
            #pragma unroll
            for (int mi = 0; mi < 2; ++mi) {
                int e0 = we * 32 + mi * 16 + lhi * 4;
                f32x4 v = vjr[ni][mi];
                f32x4 r = acc[mi][ni];
                f32x4 o;
                o.x = r[0] * v.x; o.y = r[1] * v.y;
                o.z = r[2] * v.z; o.w = r[3] * v.w;
                __builtin_nontemporal_store(o, reinterpret_cast<f32x4*>(op + e0));
            }
        }
    }
}

extern "C" void kernel_launch(void* const* d_in, const int* in_sizes, int n_in,
                              void* d_out, int out_size, void* d_ws, size_t ws_size,
                              hipStream_t stream) {
    (void)in_sizes; (void)n_in; (void)out_size;
    const float* femb = (const float*)d_in[0];
    const float* W    = (const float*)d_in[1];
    float* out        = (float*)d_out;

    if (ws_size >= WS_NEEDED) {
        unsigned short* fbp = (unsigned short*)d_ws;
        unsigned short* wbp = fbp + FEMB_BF_ELEMS;
        hipLaunchKernelGGL(prep_all, dim3(PREP_FEMB_BLOCKS + PREP_W_BLOCKS), dim3(256), 0, stream,
                           femb, W, fbp, wbp);
        hipLaunchKernelGGL(bilinear_bf16, dim3(NPAIRS), dim3(512), 0, stream, fbp, wbp, out);
    } else {
        hipLaunchKernelGGL(bilinear_f32, dim3(NPAIRS), dim3(512), 0, stream, femb, W, out);
    }
}

// Round 14
// 169.767 us; speedup vs baseline: 1.5564x; 1.0350x over previous
//
#include <hip/hip_runtime.h>
#include <hip/hip_bf16.h>

#define NF     32
#define ED     128
#define NBATCH 2048
#define NPAIRS 496
#define BM     128
#define NITER  (NBATCH / BM)   // 16 M-blocks per pair

typedef __attribute__((ext_vector_type(8))) short short8;   // 8 bf16 (MFMA A/B frag)
typedef __attribute__((ext_vector_type(4))) short short4v;  // 4 bf16
typedef __attribute__((ext_vector_type(4))) float f32x4;

#define FEMB_BF_ELEMS ((size_t)NF * NBATCH * ED)            // 8,388,608
#define WS_NEEDED     (FEMB_BF_ELEMS * 2)                   // ~16.8 MB
#define PREP_FEMB_BLOCKS 4096   // FEMB_BF_ELEMS / 8 / 256

// LDS-only barrier (r10 lever): orders LDS without draining the VMEM queue
// (NT stores + prefetch loads keep flowing across iterations).
#define LGKM_BARRIER() asm volatile("s_waitcnt lgkmcnt(0)\n\ts_barrier" ::: "memory")

__device__ __forceinline__ short f2bf(float x) {
    union { __hip_bfloat16 b; short s; } v;
    v.b = __float2bfloat16(x);
    return v.s;
}
__device__ __forceinline__ float bf2f(short s) {
    union { unsigned int u; float f; } v;
    v.u = ((unsigned int)(unsigned short)s) << 16;
    return v.f;
}

// ---------- Pre-pass: femb fp32 [b][f][d] -> bf16 field-major [f][b][d] ----------
// (W conversion REMOVED: it moved 48 MB serialized to save 16 MB in main.
//  W is read once per pair-block -> convert in the main kernel prologue.)
__global__ __launch_bounds__(256)
void prep_femb(const float* __restrict__ femb, unsigned short* __restrict__ fb) {
    int n = blockIdx.x * 256 + threadIdx.x;       // x8 elems
    int d8 = n & 15;
    int b  = (n >> 4) & (NBATCH - 1);
    int f  = n >> 15;
    const float* s = femb + ((size_t)b * NF + f) * ED + d8 * 8;
    f32x4 lo = __builtin_nontemporal_load(reinterpret_cast<const f32x4*>(s));
    f32x4 hi = __builtin_nontemporal_load(reinterpret_cast<const f32x4*>(s + 4));
    short8 pk;
    pk[0]=f2bf(lo.x); pk[1]=f2bf(lo.y); pk[2]=f2bf(lo.z); pk[3]=f2bf(lo.w);
    pk[4]=f2bf(hi.x); pk[5]=f2bf(hi.y); pk[6]=f2bf(hi.z); pk[7]=f2bf(hi.w);
    *reinterpret_cast<short8*>(fb + ((size_t)f * NBATCH + b) * ED + d8 * 8) = pk;
}

// LDS layout (both tiles): 128 rows x 256 B, swizzled:
//   byte(row, col) = row*256 + (col ^ ((row & 15) << 4))   -> conflict-free ds_read_b128

// ---------- Main kernel: r13 structure, W staged fp32->bf16 in prologue ----------
// p = (bid&7)*62 + (bid>>3): chunked pair->XCD swizzle (r13). All 496 blocks
// co-resident; consecutive pairs share fi -> vi planes L2-hot per XCD.
__global__ __launch_bounds__(512, 2)
void bilinear_bf16(const unsigned short* __restrict__ fb,
                   const float* __restrict__ W,
                   float* __restrict__ out)
{
    __shared__ unsigned char ldsW[128 * 256];
    __shared__ unsigned char ldsA[128 * 256];

    const int bid = blockIdx.x;
    const int p   = (bid & 7) * (NPAIRS / 8) + (bid >> 3);   // chunked XCD swizzle

    int fi = 0, rem = p;
    while (rem >= NF - 1 - fi) { rem -= NF - 1 - fi; ++fi; }
    const int fj = fi + 1 + rem;

    const int t    = threadIdx.x;
    const int lane = t & 63;
    const int wave = t >> 6;

    // ---- Stage W once: fp32 NT loads -> bf16 cvt -> swizzled LDS ----
    // Read-once data; 64 KB/block, overlapped across 496 block prologues.
    {
        const float* wp = W + (size_t)p * (ED * ED);
        #pragma unroll
        for (int it = 0; it < 4; ++it) {
            int idx8 = it * 4096 + t * 8;
            int e = idx8 >> 7, d = idx8 & 127;
            const float* s = wp + (size_t)e * ED + d;
            f32x4 lo = __builtin_nontemporal_load(reinterpret_cast<const f32x4*>(s));
            f32x4 hi = __builtin_nontemporal_load(reinterpret_cast<const f32x4*>(s + 4));
            short8 pk;
            pk[0]=f2bf(lo.x); pk[1]=f2bf(lo.y); pk[2]=f2bf(lo.z); pk[3]=f2bf(lo.w);
            pk[4]=f2bf(hi.x); pk[5]=f2bf(hi.y); pk[6]=f2bf(hi.z); pk[7]=f2bf(hi.w);
            *reinterpret_cast<short8*>(ldsW + e * 256 + ((d * 2) ^ ((e & 15) << 4))) = pk;
        }
    }

    // vi staging coords: thread covers rows {r_, r_+32, r_+64, r_+96} at d_..d_+7
    const int r_ = t >> 4;
    const int d_ = (t * 8) & 127;
    const unsigned short* fiPlane = fb + (size_t)fi * NBATCH * ED;
    const unsigned short* fjPlane = fb + (size_t)fj * NBATCH * ED;

    const int we  = wave & 3;       // e-quadrant
    const int wb_ = wave >> 2;      // b-half
    const int lhi = lane >> 4;
    const int llo = lane & 15;

    short8 stg[4];
    #pragma unroll
    for (int q = 0; q < 4; ++q)
        stg[q] = *reinterpret_cast<const short8*>(fiPlane + (size_t)(r_ + q * 32) * ED + d_);

    for (int mb = 0; mb < NITER; ++mb) {
        const int b0 = mb * BM;

        // ---- A-write: staged bf16 -> swizzled LDS ----
        #pragma unroll
        for (int q = 0; q < 4; ++q) {
            int r = r_ + q * 32;
            *reinterpret_cast<short8*>(ldsA + r * 256 + ((d_ * 2) ^ ((r & 15) << 4))) = stg[q];
        }
        LGKM_BARRIER();   // A (and W on first iter) visible; VMEM NOT drained

        // ---- Issue next vi prefetch ----
        if (mb + 1 < NITER) {
            const unsigned short* base = fiPlane + (size_t)((mb + 1) * BM + r_) * ED + d_;
            #pragma unroll
            for (int q = 0; q < 4; ++q)
                stg[q] = *reinterpret_cast<const short8*>(base + (size_t)q * 32 * ED);
        }

        // ---- Prefetch vj (bf16) for epilogue ----
        short4v vjr[4][2];
        #pragma unroll
        for (int ni = 0; ni < 4; ++ni) {
            int b = b0 + wb_ * 64 + ni * 16 + llo;
            const unsigned short* vj = fjPlane + (size_t)b * ED;
            #pragma unroll
            for (int mi = 0; mi < 2; ++mi) {
                int e0 = we * 32 + mi * 16 + lhi * 4;
                vjr[ni][mi] = *reinterpret_cast<const short4v*>(vj + e0);
            }
        }

        // ---- Compute: D[e][b] = W . vi^T ----
        f32x4 acc[2][4] = {};
        #pragma unroll
        for (int kk = 0; kk < 4; ++kk) {
            const int db = kk * 64 + lhi * 16;
            short8 a[2], b[4];
            #pragma unroll
            for (int mi = 0; mi < 2; ++mi) {
                int e = we * 32 + mi * 16 + llo;
                a[mi] = *reinterpret_cast<const short8*>(ldsW + e * 256 + (db ^ (llo << 4)));
            }
            #pragma unroll
            for (int ni = 0; ni < 4; ++ni) {
                int r = wb_ * 64 + ni * 16 + llo;
                b[ni] = *reinterpret_cast<const short8*>(ldsA + r * 256 + (db ^ (llo << 4)));
            }
            #pragma unroll
            for (int mi = 0; mi < 2; ++mi)
                #pragma unroll
                for (int ni = 0; ni < 4; ++ni)
                    acc[mi][ni] = __builtin_amdgcn_mfma_f32_16x16x32_bf16(a[mi], b[ni], acc[mi][ni], 0, 0, 0);
        }
        LGKM_BARRIER();   // ds_reads of ldsA done -> next iter may overwrite

        // ---- Epilogue: out = D * vj, NT stores ----
        #pragma unroll
        for (int ni = 0; ni < 4; ++ni) {
            int b = b0 + wb_ * 64 + ni * 16 + llo;
            float* op = out + ((size_t)b * NPAIRS + p) * ED;
            #pragma unroll
            for (int mi = 0; mi < 2; ++mi) {
                int e0 = we * 32 + mi * 16 + lhi * 4;
                short4v vs = vjr[ni][mi];
                f32x4 r = acc[mi][ni];
                f32x4 o;
                o.x = r[0] * bf2f(vs[0]); o.y = r[1] * bf2f(vs[1]);
                o.z = r[2] * bf2f(vs[2]); o.w = r[3] * bf2f(vs[3]);
                __builtin_nontemporal_store(o, reinterpret_cast<f32x4*>(op + e0));
            }
        }
    }
}

// ---------- Fallback (fp32 inputs) if ws too small ----------
__global__ __launch_bounds__(512, 2)
void bilinear_f32(const float* __restrict__ femb,
                  const float* __restrict__ W,
                  float* __restrict__ out)
{
    __shared__ unsigned char ldsW[128 * 256];
    __shared__ unsigned char ldsA[128 * 256];

    const int p = blockIdx.x;
    int fi = 0, rem = p;
    while (rem >= NF - 1 - fi) { rem -= NF - 1 - fi; ++fi; }
    const int fj = fi + 1 + rem;

    const int t    = threadIdx.x;
    const int lane = t & 63;
    const int wave = t >> 6;

    {
        const float* wp = W + (size_t)p * (ED * ED);
        #pragma unroll
        for (int it = 0; it < 4; ++it) {
            int idx8 = it * 4096 + t * 8;
            int e = idx8 >> 7, d = idx8 & 127;
            const float* s = wp + (size_t)e * ED + d;
            f32x4 lo = __builtin_nontemporal_load(reinterpret_cast<const f32x4*>(s));
            f32x4 hi = __builtin_nontemporal_load(reinterpret_cast<const f32x4*>(s + 4));
            short8 pk;
            pk[0]=f2bf(lo.x); pk[1]=f2bf(lo.y); pk[2]=f2bf(lo.z); pk[3]=f2bf(lo.w);
            pk[4]=f2bf(hi.x); pk[5]=f2bf(hi.y); pk[6]=f2bf(hi.z); pk[7]=f2bf(hi.w);
            *reinterpret_cast<short8*>(ldsW + e * 256 + ((d * 2) ^ ((e & 15) << 4))) = pk;
        }
    }

    const int r_ = t >> 4;
    const int d_ = (t * 8) & 127;
    const size_t ROWSTRIDE32 = (size_t)32 * NF * ED;

    const int we  = wave & 3;
    const int wb_ = wave >> 2;
    const int lhi = lane >> 4;
    const int llo = lane & 15;

    f32x4 stg[8];
    {
        const float* base = femb + ((size_t)r_ * NF + fi) * ED + d_;
        #pragma unroll
        for (int q = 0; q < 4; ++q) {
            const float* s = base + (size_t)q * ROWSTRIDE32;
            stg[2*q]   = *reinterpret_cast<const f32x4*>(s);
            stg[2*q+1] = *reinterpret_cast<const f32x4*>(s + 4);
        }
    }

    for (int mb = 0; mb < NITER; ++mb) {
        const int b0 = mb * BM;
        #pragma unroll
        for (int q = 0; q < 4; ++q) {
            int r = r_ + q * 32;
            f32x4 lo = stg[2*q], hi = stg[2*q+1];
            short8 pk;
            pk[0]=f2bf(lo.x); pk[1]=f2bf(lo.y); pk[2]=f2bf(lo.z); pk[3]=f2bf(lo.w);
            pk[4]=f2bf(hi.x); pk[5]=f2bf(hi.y); pk[6]=f2bf(hi.z); pk[7]=f2bf(hi.w);
            *reinterpret_cast<short8*>(ldsA + r * 256 + ((d_ * 2) ^ ((r & 15) << 4))) = pk;
        }
        __syncthreads();

        if (mb + 1 < NITER) {
            const float* base = femb + ((size_t)((mb + 1) * BM + r_) * NF + fi) * ED + d_;
            #pragma unroll
            for (int q = 0; q < 4; ++q) {
                const float* s = base + (size_t)q * ROWSTRIDE32;
                stg[2*q]   = *reinterpret_cast<const f32x4*>(s);
                stg[2*q+1] = *reinterpret_cast<const f32x4*>(s + 4);
            }
        }

        f32x4 vjr[4][2];
        #pragma unroll
        for (int ni = 0; ni < 4; ++ni) {
            int b = b0 + wb_ * 64 + ni * 16 + llo;
            const float* vj = femb + ((size_t)b * NF + fj) * ED;
            #pragma unroll
            for (int mi = 0; mi < 2; ++mi) {
                int e0 = we * 32 + mi * 16 + lhi * 4;
                vjr[ni][mi] = *reinterpret_cast<const f32x4*>(vj + e0);
            }
        }

        f32x4 acc[2][4] = {};
        #pragma unroll
        for (int kk = 0; kk < 4; ++kk) {
            const int db = kk * 64 + lhi * 16;
            short8 a[2], b[4];
            #pragma unroll
            for (int mi = 0; mi < 2; ++mi) {
                int e = we * 32 + mi * 16 + llo;
                a[mi] = *reinterpret_cast<const short8*>(ldsW + e * 256 + (db ^ (llo << 4)));
            }
            #pragma unroll
            for (int ni = 0; ni < 4; ++ni) {
                int r = wb_ * 64 + ni * 16 + llo;
                b[ni] = *reinterpret_cast<const short8*>(ldsA + r * 256 + (db ^ (llo << 4)));
            }
            #pragma unroll
            for (int mi = 0; mi < 2; ++mi)
                #pragma unroll
                for (int ni = 0; ni < 4; ++ni)
                    acc[mi][ni] = __builtin_amdgcn_mfma_f32_16x16x32_bf16(a[mi], b[ni], acc[mi][ni], 0, 0, 0);
        }
        __syncthreads();

        #pragma unroll
        for (int ni = 0; ni < 4; ++ni) {
            int b = b0 + wb_ * 64 + ni * 16 + llo;
            float* op = out + ((size_t)b * NPAIRS + p) * ED;
            #pragma unroll
            for (int mi = 0; mi < 2; ++mi) {
                int e0 = we * 32 + mi * 16 + lhi * 4;
                f32x4 v = vjr[ni][mi];
                f32x4 r = acc[mi][ni];
                f32x4 o;
                o.x = r[0] * v.x; o.y = r[1] * v.y;
                o.z = r[2] * v.z; o.w = r[3] * v.w;
                __builtin_nontemporal_store(o, reinterpret_cast<f32x4*>(op + e0));
            }
        }
    }
}

extern "C" void kernel_launch(void* const* d_in, const int* in_sizes, int n_in,
                              void* d_out, int out_size, void* d_ws, size_t ws_size,
                              hipStream_t stream) {
    (void)in_sizes; (void)n_in; (void)out_size;
    const float* femb = (const float*)d_in[0];
    const float* W    = (const float*)d_in[1];
    float* out        = (float*)d_out;

    if (ws_size >= WS_NEEDED) {
        unsigned short* fbp = (unsigned short*)d_ws;
        hipLaunchKernelGGL(prep_femb, dim3(PREP_FEMB_BLOCKS), dim3(256), 0, stream, femb, fbp);
        hipLaunchKernelGGL(bilinear_bf16, dim3(NPAIRS), dim3(512), 0, stream, fbp, W, out);
    } else {
        hipLaunchKernelGGL(bilinear_f32, dim3(NPAIRS), dim3(512), 0, stream, femb, W, out);
    }
}

// Round 15
// 122.200 us; speedup vs baseline: 2.1622x; 1.3893x over previous
//
#include <hip/hip_runtime.h>
#include <hip/hip_bf16.h>

#define NF     32
#define ED     128
#define NBATCH 2048
#define NPAIRS 496
#define BM     128
#define NITER  (NBATCH / BM)   // 16 M-blocks per pair

typedef __attribute__((ext_vector_type(8))) short short8;   // 8 bf16 (MFMA A/B frag)
typedef __attribute__((ext_vector_type(4))) short short4v;  // 4 bf16
typedef __attribute__((ext_vector_type(4))) float f32x4;

#define FEMB_BF_ELEMS ((size_t)NF * NBATCH * ED)            // 8,388,608
#define WS_NEEDED     (FEMB_BF_ELEMS * 2)                   // ~16.8 MB
#define PREP_FEMB_BLOCKS 4096   // FEMB_BF_ELEMS / 8 / 256

// LDS-only barrier: orders LDS without draining the VMEM queue
// (NT stores + prefetch loads keep flowing across iterations).
#define LGKM_BARRIER() asm volatile("s_waitcnt lgkmcnt(0)\n\ts_barrier" ::: "memory")

__device__ __forceinline__ short f2bf(float x) {
    union { __hip_bfloat16 b; short s; } v;
    v.b = __float2bfloat16(x);
    return v.s;
}
__device__ __forceinline__ float bf2f(short s) {
    union { unsigned int u; float f; } v;
    v.u = ((unsigned int)(unsigned short)s) << 16;
    return v.f;
}

// ---------- Pre-pass: femb fp32 [b][f][d] -> bf16 field-major [f][b][d] ----------
__global__ __launch_bounds__(256)
void prep_femb(const float* __restrict__ femb, unsigned short* __restrict__ fb) {
    int n = blockIdx.x * 256 + threadIdx.x;       // x8 elems
    int d8 = n & 15;
    int b  = (n >> 4) & (NBATCH - 1);
    int f  = n >> 15;
    const float* s = femb + ((size_t)b * NF + f) * ED + d8 * 8;
    f32x4 lo = __builtin_nontemporal_load(reinterpret_cast<const f32x4*>(s));
    f32x4 hi = __builtin_nontemporal_load(reinterpret_cast<const f32x4*>(s + 4));
    short8 pk;
    pk[0]=f2bf(lo.x); pk[1]=f2bf(lo.y); pk[2]=f2bf(lo.z); pk[3]=f2bf(lo.w);
    pk[4]=f2bf(hi.x); pk[5]=f2bf(hi.y); pk[6]=f2bf(hi.z); pk[7]=f2bf(hi.w);
    *reinterpret_cast<short8*>(fb + ((size_t)f * NBATCH + b) * ED + d8 * 8) = pk;
}

// LDS input-tile layout: 128 rows x 256 B, byte(row,col)=row*256+(col^((row&15)<<4))
// LDS out-tile layout (epilogue, reuses ldsA): 64 rows x 512 B fp32,
//   byte(row, ebyte) = row*512 + (ebyte ^ ((row&15)<<4))

__global__ __launch_bounds__(512, 2)
void bilinear_bf16(const unsigned short* __restrict__ fb,
                   const float* __restrict__ W,
                   float* __restrict__ out)
{
    __shared__ unsigned char ldsW[128 * 256];
    __shared__ unsigned char ldsA[128 * 256];   // vi tile; reused as 64x512B out tile

    const int bid = blockIdx.x;
    const int p   = (bid & 7) * (NPAIRS / 8) + (bid >> 3);   // chunked XCD swizzle

    int fi = 0, rem = p;
    while (rem >= NF - 1 - fi) { rem -= NF - 1 - fi; ++fi; }
    const int fj = fi + 1 + rem;

    const int t    = threadIdx.x;
    const int lane = t & 63;
    const int wave = t >> 6;

    // ---- Stage W once: fp32 NT loads -> bf16 cvt -> swizzled LDS ----
    {
        const float* wp = W + (size_t)p * (ED * ED);
        #pragma unroll
        for (int it = 0; it < 4; ++it) {
            int idx8 = it * 4096 + t * 8;
            int e = idx8 >> 7, d = idx8 & 127;
            const float* s = wp + (size_t)e * ED + d;
            f32x4 lo = __builtin_nontemporal_load(reinterpret_cast<const f32x4*>(s));
            f32x4 hi = __builtin_nontemporal_load(reinterpret_cast<const f32x4*>(s + 4));
            short8 pk;
            pk[0]=f2bf(lo.x); pk[1]=f2bf(lo.y); pk[2]=f2bf(lo.z); pk[3]=f2bf(lo.w);
            pk[4]=f2bf(hi.x); pk[5]=f2bf(hi.y); pk[6]=f2bf(hi.z); pk[7]=f2bf(hi.w);
            *reinterpret_cast<short8*>(ldsW + e * 256 + ((d * 2) ^ ((e & 15) << 4))) = pk;
        }
    }

    // vi staging coords
    const int r_ = t >> 4;
    const int d_ = (t * 8) & 127;
    const unsigned short* fiPlane = fb + (size_t)fi * NBATCH * ED;
    const unsigned short* fjPlane = fb + (size_t)fj * NBATCH * ED;

    const int we  = wave & 3;       // e-quadrant
    const int wb_ = wave >> 2;      // b-half
    const int lhi = lane >> 4;
    const int llo = lane & 15;

    short8 stg[4];
    #pragma unroll
    for (int q = 0; q < 4; ++q)
        stg[q] = *reinterpret_cast<const short8*>(fiPlane + (size_t)(r_ + q * 32) * ED + d_);

    for (int mb = 0; mb < NITER; ++mb) {
        const int b0 = mb * BM;

        // ---- A-write: staged bf16 -> swizzled LDS ----
        #pragma unroll
        for (int q = 0; q < 4; ++q) {
            int r = r_ + q * 32;
            *reinterpret_cast<short8*>(ldsA + r * 256 + ((d_ * 2) ^ ((r & 15) << 4))) = stg[q];
        }
        LGKM_BARRIER();

        // ---- Issue next vi prefetch ----
        if (mb + 1 < NITER) {
            const unsigned short* base = fiPlane + (size_t)((mb + 1) * BM + r_) * ED + d_;
            #pragma unroll
            for (int q = 0; q < 4; ++q)
                stg[q] = *reinterpret_cast<const short8*>(base + (size_t)q * 32 * ED);
        }

        // ---- Compute: D[e][b] = W . vi^T ----
        f32x4 acc[2][4] = {};
        #pragma unroll
        for (int kk = 0; kk < 4; ++kk) {
            const int db = kk * 64 + lhi * 16;
            short8 a[2], b[4];
            #pragma unroll
            for (int mi = 0; mi < 2; ++mi) {
                int e = we * 32 + mi * 16 + llo;
                a[mi] = *reinterpret_cast<const short8*>(ldsW + e * 256 + (db ^ (llo << 4)));
            }
            #pragma unroll
            for (int ni = 0; ni < 4; ++ni) {
                int r = wb_ * 64 + ni * 16 + llo;
                b[ni] = *reinterpret_cast<const short8*>(ldsA + r * 256 + (db ^ (llo << 4)));
            }
            #pragma unroll
            for (int mi = 0; mi < 2; ++mi)
                #pragma unroll
                for (int ni = 0; ni < 4; ++ni)
                    acc[mi][ni] = __builtin_amdgcn_mfma_f32_16x16x32_bf16(a[mi], b[ni], acc[mi][ni], 0, 0, 0);
        }
        LGKM_BARRIER();   // all MFMA ldsA reads done -> safe to reuse as out tile

        // ---- Epilogue: LDS-transpose -> CONTIGUOUS 1KB NT stores ----
        // Pass h: waves with wb_==h write their acc quadrants into a 64x512B
        // fp32 tile (rows = b-local), then ALL waves read whole rows and store
        // out[b][p][0..127] as 512B-contiguous segments (2 rows per instr).
        #pragma unroll
        for (int h = 0; h < 2; ++h) {
            if (wb_ == h) {
                #pragma unroll
                for (int ni = 0; ni < 4; ++ni) {
                    int row = ni * 16 + llo;                       // 0..63
                    #pragma unroll
                    for (int mi = 0; mi < 2; ++mi) {
                        int ebyte = (we * 32 + mi * 16 + lhi * 4) * 4;
                        int byte  = row * 512 + (ebyte ^ ((row & 15) << 4));
                        *reinterpret_cast<f32x4*>(ldsA + byte) = acc[mi][ni];
                    }
                }
            }
            LGKM_BARRIER();   // out-tile half visible to all waves
            #pragma unroll
            for (int s = 0; s < 4; ++s) {
                int row  = wave * 8 + s * 2 + (lane >> 5);          // 0..63
                int e0   = (lane & 31) * 4;                         // 0..124
                int byte = row * 512 + ((e0 * 4) ^ ((row & 15) << 4));
                f32x4 r = *reinterpret_cast<const f32x4*>(ldsA + byte);
                int b = b0 + h * 64 + row;
                short4v vs = *reinterpret_cast<const short4v*>(
                    fjPlane + (size_t)b * ED + e0);                 // contiguous 8B/lane
                f32x4 o;
                o.x = r.x * bf2f(vs[0]); o.y = r.y * bf2f(vs[1]);
                o.z = r.z * bf2f(vs[2]); o.w = r.w * bf2f(vs[3]);
                float* op = out + ((size_t)b * NPAIRS + p) * ED + e0;
                __builtin_nontemporal_store(o, reinterpret_cast<f32x4*>(op));
            }
            LGKM_BARRIER();   // reads done -> next write (h=1 or next A-write) safe
        }
    }
}

// ---------- Fallback (fp32 inputs) if ws too small ----------
__global__ __launch_bounds__(512, 2)
void bilinear_f32(const float* __restrict__ femb,
                  const float* __restrict__ W,
                  float* __restrict__ out)
{
    __shared__ unsigned char ldsW[128 * 256];
    __shared__ unsigned char ldsA[128 * 256];

    const int p = blockIdx.x;
    int fi = 0, rem = p;
    while (rem >= NF - 1 - fi) { rem -= NF - 1 - fi; ++fi; }
    const int fj = fi + 1 + rem;

    const int t    = threadIdx.x;
    const int lane = t & 63;
    const int wave = t >> 6;

    {
        const float* wp = W + (size_t)p * (ED * ED);
        #pragma unroll
        for (int it = 0; it < 4; ++it) {
            int idx8 = it * 4096 + t * 8;
            int e = idx8 >> 7, d = idx8 & 127;
            const float* s = wp + (size_t)e * ED + d;
            f32x4 lo = __builtin_nontemporal_load(reinterpret_cast<const f32x4*>(s));
            f32x4 hi = __builtin_nontemporal_load(reinterpret_cast<const f32x4*>(s + 4));
            short8 pk;
            pk[0]=f2bf(lo.x); pk[1]=f2bf(lo.y); pk[2]=f2bf(lo.z); pk[3]=f2bf(lo.w);
            pk[4]=f2bf(hi.x); pk[5]=f2bf(hi.y); pk[6]=f2bf(hi.z); pk[7]=f2bf(hi.w);
            *reinterpret_cast<short8*>(ldsW + e * 256 + ((d * 2) ^ ((e & 15) << 4))) = pk;
        }
    }

    const int r_ = t >> 4;
    const int d_ = (t * 8) & 127;
    const size_t ROWSTRIDE32 = (size_t)32 * NF * ED;

    const int we  = wave & 3;
    const int wb_ = wave >> 2;
    const int lhi = lane >> 4;
    const int llo = lane & 15;

    f32x4 stg[8];
    {
        const float* base = femb + ((size_t)r_ * NF + fi) * ED + d_;
        #pragma unroll
        for (int q = 0; q < 4; ++q) {
            const float* s = base + (size_t)q * ROWSTRIDE32;
            stg[2*q]   = *reinterpret_cast<const f32x4*>(s);
            stg[2*q+1] = *reinterpret_cast<const f32x4*>(s + 4);
        }
    }

    for (int mb = 0; mb < NITER; ++mb) {
        const int b0 = mb * BM;
        #pragma unroll
        for (int q = 0; q < 4; ++q) {
            int r = r_ + q * 32;
            f32x4 lo = stg[2*q], hi = stg[2*q+1];
            short8 pk;
            pk[0]=f2bf(lo.x); pk[1]=f2bf(lo.y); pk[2]=f2bf(lo.z); pk[3]=f2bf(lo.w);
            pk[4]=f2bf(hi.x); pk[5]=f2bf(hi.y); pk[6]=f2bf(hi.z); pk[7]=f2bf(hi.w);
            *reinterpret_cast<short8*>(ldsA + r * 256 + ((d_ * 2) ^ ((r & 15) << 4))) = pk;
        }
        __syncthreads();

        if (mb + 1 < NITER) {
            const float* base = femb + ((size_t)((mb + 1) * BM + r_) * NF + fi) * ED + d_;
            #pragma unroll
            for (int q = 0; q < 4; ++q) {
                const float* s = base + (size_t)q * ROWSTRIDE32;
                stg[2*q]   = *reinterpret_cast<const f32x4*>(s);
                stg[2*q+1] = *reinterpret_cast<const f32x4*>(s + 4);
            }
        }

        f32x4 vjr[4][2];
        #pragma unroll
        for (int ni = 0; ni < 4; ++ni) {
            int b = b0 + wb_ * 64 + ni * 16 + llo;
            const float* vj = femb + ((size_t)b * NF + fj) * ED;
            #pragma unroll
            for (int mi = 0; mi < 2; ++mi) {
                int e0 = we * 32 + mi * 16 + lhi * 4;
                vjr[ni][mi] = *reinterpret_cast<const f32x4*>(vj + e0);
            }
        }

        f32x4 acc[2][4] = {};
        #pragma unroll
        for (int kk = 0; kk < 4; ++kk) {
            const int db = kk * 64 + lhi * 16;
            short8 a[2], b[4];
            #pragma unroll
            for (int mi = 0; mi < 2; ++mi) {
                int e = we * 32 + mi * 16 + llo;
                a[mi] = *reinterpret_cast<const short8*>(ldsW + e * 256 + (db ^ (llo << 4)));
            }
            #pragma unroll
            for (int ni = 0; ni < 4; ++ni) {
                int r = wb_ * 64 + ni * 16 + llo;
                b[ni] = *reinterpret_cast<const short8*>(ldsA + r * 256 + (db ^ (llo << 4)));
            }
            #pragma unroll
            for (int mi = 0; mi < 2; ++mi)
                #pragma unroll
                for (int ni = 0; ni < 4; ++ni)
                    acc[mi][ni] = __builtin_amdgcn_mfma_f32_16x16x32_bf16(a[mi], b[ni], acc[mi][ni], 0, 0, 0);
        }
        __syncthreads();

        #pragma unroll
        for (int ni = 0; ni < 4; ++ni) {
            int b = b0 + wb_ * 64 + ni * 16 + llo;
            float* op = out + ((size_t)b * NPAIRS + p) * ED;
            #pragma unroll
            for (int mi = 0; mi < 2; ++mi) {
                int e0 = we * 32 + mi * 16 + lhi * 4;
                f32x4 v = vjr[ni][mi];
                f32x4 r = acc[mi][ni];
                f32x4 o;
                o.x = r[0] * v.x; o.y = r[1] * v.y;
                o.z = r[2] * v.z; o.w = r[3] * v.w;
                __builtin_nontemporal_store(o, reinterpret_cast<f32x4*>(op + e0));
            }
        }
    }
}

extern "C" void kernel_launch(void* const* d_in, const int* in_sizes, int n_in,
                              void* d_out, int out_size, void* d_ws, size_t ws_size,
                              hipStream_t stream) {
    (void)in_sizes; (void)n_in; (void)out_size;
    const float* femb = (const float*)d_in[0];
    const float* W    = (const float*)d_in[1];
    float* out        = (float*)d_out;

    if (ws_size >= WS_NEEDED) {
        unsigned short* fbp = (unsigned short*)d_ws;
        hipLaunchKernelGGL(prep_femb, dim3(PREP_FEMB_BLOCKS), dim3(256), 0, stream, femb, fbp);
        hipLaunchKernelGGL(bilinear_bf16, dim3(NPAIRS), dim3(512), 0, stream, fbp, W, out);
    } else {
        hipLaunchKernelGGL(bilinear_f32, dim3(NPAIRS), dim3(512), 0, stream, femb, W, out);
    }
}